// Round 10
// baseline (1596.984 us; speedup 1.0000x reference)
//
#include <hip/hip_runtime.h>
#include <hip/hip_bf16.h>
#include <stdint.h>

#define CIN   448
#define DP    100
#define NPIX  4096
#define LNUM  4096
#define KQ    5050      // packed upper-triangle columns
#define KLIN  5150      // + 100 linear columns
#define KTOT  5184      // padded to 81*64
#define KSTEPS (KTOT / 64)
#define OUTHW 256

typedef _Float16 f16_t;
typedef _Float16 f16x8 __attribute__((ext_vector_type(8)));
typedef float    f32x4 __attribute__((ext_vector_type(4)));
typedef unsigned short u16x8 __attribute__((ext_vector_type(8)));

static __device__ __forceinline__ int tri_off(int d) { return (d * (201 - d)) >> 1; }

static __device__ __forceinline__ void unpack_tri(int k, int& d, int& e) {
    int dd = (int)((201.0f - sqrtf(40401.0f - 8.0f * (float)k)) * 0.5f);
    if (dd < 0) dd = 0;
    if (dd > 99) dd = 99;
    while (tri_off(dd + 1) <= k) ++dd;
    while (tri_off(dd) > k) --dd;
    d = dd;
    e = dd + (k - tri_off(dd));
}

static __device__ __forceinline__ unsigned f2u(float x) {
    unsigned b = __float_as_uint(x);
    return (b & 0x80000000u) ? ~b : (b | 0x80000000u);
}
static __device__ __forceinline__ float u2f(unsigned u) {
    unsigned b = (u & 0x80000000u) ? (u & 0x7FFFFFFFu) : ~u;
    return __uint_as_float(b);
}

static __device__ __forceinline__ void gload_lds16(const f16_t* g, f16_t* l) {
    __builtin_amdgcn_global_load_lds((const __attribute__((address_space(1))) unsigned*)g,
                                     (__attribute__((address_space(3))) unsigned*)l,
                                     16, 0, 0);
}

// ---------------- kernel 0: tri-unpack LUT + init per-row min ----------------
__global__ void k_lut(unsigned short* __restrict__ lut, unsigned* __restrict__ mind) {
    int k = blockIdx.x * 256 + threadIdx.x;
    if (k < KTOT) {
        int d = 0, e = 0;
        if (k < KQ) unpack_tri(k, d, e);
        lut[k] = (unsigned short)(d | (e << 8));
    }
    if (k < NPIX) mind[k] = 0xFFFFFFFFu;
}

// ---------------- kernel 1: projection f[n,d] = feat[:,n] . w[d,:] + b[d] ----------------
__global__ void k_proj(const float* __restrict__ feat, const float* __restrict__ w,
                       const float* __restrict__ b, float* __restrict__ f) {
    int gid = blockIdx.x * 256 + threadIdx.x;   // 409600 = 4096*100
    int n = gid & 4095;
    int d = gid >> 12;
    float acc = b[d];
    const float* wd = w + d * CIN;
    #pragma unroll 4
    for (int c = 0; c < CIN; ++c) acc += feat[c * 4096 + n] * wd[c];
    f[n * DP + d] = acc;
}

// ---------------- kernel 2: build A, tiled+swizzled, vectorized stores ----------------
__global__ __launch_bounds__(256) void k_buildA(const float* __restrict__ f, const unsigned short* __restrict__ lut,
                                                f16_t* __restrict__ A) {
    __shared__ float fr[DP];
    int n = blockIdx.x;
    int t = threadIdx.x;
    if (t < DP) fr[t] = f[n * DP + t];
    __syncthreads();
    int r  = n & 127;
    int rsw = (r & 7) << 3;
    f16_t* tileBase = A + (size_t)(n >> 7) * KSTEPS * 8192;
    for (int g = t; g < KTOT / 8; g += 256) {
        int k0 = g * 8;
        u16x8 lu = *(const u16x8*)&lut[k0];
        f16x8 v;
        #pragma unroll
        for (int j = 0; j < 8; ++j) {
            int k = k0 + j;
            float x;
            if (k < KQ) {
                int d = lu[j] & 255, e = lu[j] >> 8;
                x = fr[d] * fr[e];
            } else if (k < KLIN) {
                x = fr[k - KQ];
            } else {
                x = 0.0f;
            }
            v[j] = (f16_t)x;
        }
        int kt = k0 >> 6, kin = k0 & 63;
        *(f16x8*)&tileBase[kt * 8192 + r * 64 + ((kin & 56) ^ rsw)] = v;
    }
}

// ---------------- kernel 3: build B, tiled+swizzled + const[l] ----------------
__global__ __launch_bounds__(256) void k_buildB(const float* __restrict__ icov, const float* __restrict__ mean,
                                                const unsigned short* __restrict__ lut,
                                                f16_t* __restrict__ Bm, float* __restrict__ constl) {
    __shared__ float ic[DP * 101];   // stride 101: conflict-free column reads
    __shared__ float ml[DP];
    __shared__ float wv[DP];
    __shared__ float part[DP];
    int l = blockIdx.x;
    int t = threadIdx.x;
    const float4* src4 = (const float4*)(icov + (size_t)l * DP * DP);
    for (int i4 = t; i4 < DP * DP / 4; i4 += 256) {
        float4 v = src4[i4];
        int flat = i4 * 4;
        int row = flat / 100;
        int col = flat - row * 100;   // 100 % 4 == 0: never crosses a row
        float* dst = &ic[row * 101 + col];
        dst[0] = v.x; dst[1] = v.y; dst[2] = v.z; dst[3] = v.w;
    }
    if (t < DP) ml[t] = mean[t * LNUM + l];
    __syncthreads();
    if (t < DP) {
        float icm = 0.f, ictm = 0.f;
        for (int e = 0; e < DP; ++e) {
            icm  += ic[t * 101 + e] * ml[e];
            ictm += ic[e * 101 + t] * ml[e];
        }
        wv[t]   = icm + ictm;        // (S m)_t  with S = IC + IC^T
        part[t] = ml[t] * icm;       // for m^T IC m
    }
    __syncthreads();
    if (t == 0) {
        float c = 0.f;
        for (int d = 0; d < DP; ++d) c += part[d];
        constl[l] = c;               // m^T IC m
    }
    int r  = l & 127;
    int rsw = (r & 7) << 3;
    f16_t* tileBase = Bm + (size_t)(l >> 7) * KSTEPS * 8192;
    for (int g = t; g < KTOT / 8; g += 256) {
        int k0 = g * 8;
        u16x8 lu = *(const u16x8*)&lut[k0];
        f16x8 v;
        #pragma unroll
        for (int j = 0; j < 8; ++j) {
            int k = k0 + j;
            float x;
            if (k < KQ) {
                int d = lu[j] & 255, e = lu[j] >> 8;
                float s = ic[d * 101 + e] + ic[e * 101 + d];
                x = (d == e) ? 0.5f * s : s;
            } else if (k < KLIN) {
                x = -wv[k - KQ];
            } else {
                x = 0.0f;
            }
            v[j] = (f16_t)x;
        }
        int kt = k0 >> 6, kin = k0 & 63;
        *(f16x8*)&tileBase[kt * 8192 + r * 64 + ((kin & 56) ^ rsw)] = v;
    }
}

// ---------------- kernel 4: 256^2-tile MFMA GEMM, SINGLE 64KB LDS buffer ----------------
// Rationale (r9 counters + LDS-BW arithmetic): the gemm is LDS-bandwidth-bound.
// 8 waves x 128x64-per-wave reads 24KB LDS per wave-K-step for 1.05 MFLOP (0.023 B/FLOP)
// vs 128^2's 0.031 B/FLOP. Fragment mapping + epilogue verbatim from the Round-6-verified
// 256^2 kernel; dbuf dropped (64KB -> 2 blocks/CU keeps cross-block latency hiding).
__global__ __launch_bounds__(512, 4) void k_gemm(const f16_t* __restrict__ A, const f16_t* __restrict__ Bm,
                                                 const float* __restrict__ constl, unsigned* __restrict__ mind) {
    __shared__ __align__(16) f16_t sA[16384];   // [half(0|1)][128 rows][64 k] swizzled, 32KB
    __shared__ __align__(16) f16_t sB[16384];   // 32KB

    int bid = blockIdx.x;                        // 256 blocks (16 x 16)
    int pid = ((bid & 7) << 5) | (bid >> 3);     // XCD swizzle, bijective (256 % 8 == 0)
    int bm = pid & 15;
    int bn = pid >> 4;

    int t = threadIdx.x;
    int lane = t & 63;
    int w = t >> 6;                              // 0..7
    int wr = w >> 2;                             // 0..1 (M)
    int wc = w & 3;                              // 0..3 (N)

    f32x4 acc[8][4];
    #pragma unroll
    for (int i = 0; i < 8; ++i)
        #pragma unroll
        for (int j = 0; j < 4; ++j) acc[i][j] = (f32x4){0.f, 0.f, 0.f, 0.f};

    // staging: wave w covers half-tile h=w>>2 (global tile 2*bm+h / 2*bn+h), chunk (w&3)
    const f16_t* Atile = A  + ((size_t)(2 * bm + (w >> 2)) * KSTEPS) * 8192 + (w & 3) * 2048 + lane * 8;
    const f16_t* Btile = Bm + ((size_t)(2 * bn + (w >> 2)) * KSTEPS) * 8192 + (w & 3) * 2048 + lane * 8;
    int sbase = (w >> 2) * 8192 + (w & 3) * 2048;

    int l15 = lane & 15;
    int xorv = (lane & 7) << 3;
    int klobase = (lane >> 4) * 8;

    for (int kt = 0; kt < KSTEPS; ++kt) {
        const f16_t* As = Atile + (size_t)kt * 8192;
        const f16_t* Bs = Btile + (size_t)kt * 8192;
        #pragma unroll
        for (int c = 0; c < 4; ++c) {
            gload_lds16(As + c * 512, &sA[sbase + c * 512]);
            gload_lds16(Bs + c * 512, &sB[sbase + c * 512]);
        }
        __syncthreads();   // vmcnt drain + barrier: both 32KB operand tiles resident
        #pragma unroll
        for (int kk = 0; kk < 2; ++kk) {
            int klo = (kk * 32 + klobase) ^ xorv;
            f16x8 bfr[4];
            #pragma unroll
            for (int ni = 0; ni < 4; ++ni) {
                int rr = (wc & 1) * 64 + ni * 16 + l15;
                bfr[ni] = *(const f16x8*)&sB[(wc >> 1) * 8192 + rr * 64 + klo];
            }
            #pragma unroll
            for (int mq = 0; mq < 2; ++mq) {
                f16x8 afr[4];
                #pragma unroll
                for (int mi = 0; mi < 4; ++mi) {
                    int rr = (mq * 4 + mi) * 16 + l15;
                    afr[mi] = *(const f16x8*)&sA[wr * 8192 + rr * 64 + klo];
                }
                __builtin_amdgcn_s_setprio(1);
                #pragma unroll
                for (int mi = 0; mi < 4; ++mi)
                    #pragma unroll
                    for (int ni = 0; ni < 4; ++ni)
                        acc[mq * 4 + mi][ni] =
                            __builtin_amdgcn_mfma_f32_16x16x32_f16(afr[mi], bfr[ni], acc[mq * 4 + mi][ni], 0, 0, 0);
                __builtin_amdgcn_s_setprio(0);
            }
        }
        __syncthreads();   // all fragment reads done before next stage overwrites
    }

    // epilogue: dist = acc + const[col]; min over block cols per row; atomicMin
    int colbase = bn * 256 + wc * 64 + l15;
    float cl[4];
    #pragma unroll
    for (int ni = 0; ni < 4; ++ni) cl[ni] = constl[colbase + ni * 16];
    #pragma unroll
    for (int mi8 = 0; mi8 < 8; ++mi8) {
        #pragma unroll
        for (int j = 0; j < 4; ++j) {
            float v = 1e30f;
            #pragma unroll
            for (int ni = 0; ni < 4; ++ni) v = fminf(v, acc[mi8][ni][j] + cl[ni]);
            #pragma unroll
            for (int s = 1; s < 16; s <<= 1) v = fminf(v, __shfl_xor(v, s, 64));
            if (l15 == 0) {
                int row = bm * 256 + wr * 128 + mi8 * 16 + (lane >> 4) * 4 + j;
                atomicMin(&mind[row], f2u(v));
            }
        }
    }
}

// ---------------- kernel 5: normalize + bilinear upsample (min/max fused per block) ----------------
__global__ __launch_bounds__(256) void k_upsample(const unsigned* __restrict__ mind, float* __restrict__ out) {
    __shared__ float smin[256], smax[256];
    int t = threadIdx.x;
    float vmin = 1e30f, vmax = -1e30f;
    for (int i = t; i < NPIX; i += 256) {
        float v = u2f(mind[i]);
        vmin = fminf(vmin, v);
        vmax = fmaxf(vmax, v);
    }
    smin[t] = vmin; smax[t] = vmax;
    __syncthreads();
    for (int s = 128; s > 0; s >>= 1) {
        if (t < s) {
            smin[t] = fminf(smin[t], smin[t + s]);
            smax[t] = fmaxf(smax[t], smax[t + s]);
        }
        __syncthreads();
    }
    float gmin = smin[0];
    float scale = 1.0f / (smax[0] - smin[0] + 1e-8f);

    int gid = blockIdx.x * 256 + t;             // 65536
    int i = gid >> 8, j = gid & 255;
    float x = fminf(fmaxf(j * 0.25f - 0.375f, 0.0f), 63.0f);
    float y = fminf(fmaxf(i * 0.25f - 0.375f, 0.0f), 63.0f);
    int x0 = (int)x, y0 = (int)y;
    int x1 = min(x0 + 1, 63), y1 = min(y0 + 1, 63);
    float fx = x - x0, fy = y - y0;
    float v00 = u2f(mind[y0 * 64 + x0]), v01 = u2f(mind[y0 * 64 + x1]);
    float v10 = u2f(mind[y1 * 64 + x0]), v11 = u2f(mind[y1 * 64 + x1]);
    float v = v00 * (1.f - fy) * (1.f - fx) + v01 * (1.f - fy) * fx
            + v10 * fy * (1.f - fx) + v11 * fy * fx;
    out[gid] = (v - gmin) * scale;
}

// ---------------- diagnostic: ws too small -> uniform 0.25 output (absmax ~0.70) ----------------
__global__ void k_diag(float* __restrict__ out) {
    int gid = blockIdx.x * 256 + threadIdx.x;
    out[gid] = 0.25f;
}

extern "C" void kernel_launch(void* const* d_in, const int* in_sizes, int n_in,
                              void* d_out, int out_size, void* d_ws, size_t ws_size,
                              hipStream_t stream) {
    const float* feat = (const float*)d_in[0];
    const float* pw   = (const float*)d_in[1];
    const float* pb   = (const float*)d_in[2];
    const float* mean = (const float*)d_in[3];
    const float* icov = (const float*)d_in[4];

    size_t need = 0;
    auto count = [&need](size_t bytes) { need = ((need + 255) & ~(size_t)255) + bytes; };
    count((size_t)NPIX * DP * 4);
    count((size_t)NPIX * KTOT * 2);
    count((size_t)LNUM * KTOT * 2);
    count((size_t)LNUM * 4);
    count((size_t)NPIX * 4);
    count((size_t)KTOT * 2);
    if (ws_size < need) {
        k_diag<<<256, 256, 0, stream>>>((float*)d_out);
        return;
    }

    char* ws = (char*)d_ws;
    size_t off = 0;
    auto alloc = [&](size_t bytes) -> void* {
        off = (off + 255) & ~(size_t)255;
        void* p = ws + off;
        off += bytes;
        return p;
    };
    float*          f      = (float*)alloc((size_t)NPIX * DP * 4);
    f16_t*          Amat   = (f16_t*)alloc((size_t)NPIX * KTOT * 2);
    f16_t*          Bmat   = (f16_t*)alloc((size_t)LNUM * KTOT * 2);
    float*          constl = (float*)alloc((size_t)LNUM * 4);
    unsigned*       mind   = (unsigned*)alloc((size_t)NPIX * 4);
    unsigned short* lut    = (unsigned short*)alloc((size_t)KTOT * 2);

    k_lut     <<<(KTOT + 255) / 256, 256, 0, stream>>>(lut, mind);
    k_proj    <<<1600, 256, 0, stream>>>(feat, pw, pb, f);
    k_buildA  <<<NPIX, 256, 0, stream>>>(f, lut, Amat);
    k_buildB  <<<LNUM, 256, 0, stream>>>(icov, mean, lut, Bmat, constl);
    k_gemm    <<<256, 512, 0, stream>>>(Amat, Bmat, constl, mind);
    k_upsample<<<256, 256, 0, stream>>>(mind, (float*)d_out);
}

// Round 11
// 361.320 us; speedup vs baseline: 4.4199x; 4.4199x over previous
//
#include <hip/hip_runtime.h>
#include <hip/hip_bf16.h>
#include <stdint.h>

#define CIN   448
#define DP    100
#define NPIX  4096
#define LNUM  4096
#define KQ    5050      // packed upper-triangle columns
#define KLIN  5150      // + 100 linear columns
#define KTOT  5184      // padded to 81*64
#define KSTEPS (KTOT / 64)
#define OUTHW 256

typedef _Float16 f16_t;
typedef _Float16 f16x8 __attribute__((ext_vector_type(8)));
typedef float    f32x16 __attribute__((ext_vector_type(16)));
typedef unsigned short u16x8 __attribute__((ext_vector_type(8)));

// Register-image tile layout for mfma_f32_32x32x16_f16:
// 128x64 K-tile = 16 blocks of 512 f16. Element (r, kin):
//   block = (r>>5)*4 + (kin>>4); in-block = ((kin>>3)&1)*256 + (r&31)*8 + (kin&7)
// A consuming lane reads f16 [block*512 + lane*8 .. +8) -- linear, conflict-free.
static __device__ __forceinline__ int tile_idx(int r, int kin) {
    return ((r >> 5) * 4 + (kin >> 4)) * 512 + ((kin >> 3) & 1) * 256 + (r & 31) * 8 + (kin & 7);
}

static __device__ __forceinline__ int tri_off(int d) { return (d * (201 - d)) >> 1; }

static __device__ __forceinline__ void unpack_tri(int k, int& d, int& e) {
    int dd = (int)((201.0f - sqrtf(40401.0f - 8.0f * (float)k)) * 0.5f);
    if (dd < 0) dd = 0;
    if (dd > 99) dd = 99;
    while (tri_off(dd + 1) <= k) ++dd;
    while (tri_off(dd) > k) --dd;
    d = dd;
    e = dd + (k - tri_off(dd));
}

static __device__ __forceinline__ unsigned f2u(float x) {
    unsigned b = __float_as_uint(x);
    return (b & 0x80000000u) ? ~b : (b | 0x80000000u);
}
static __device__ __forceinline__ float u2f(unsigned u) {
    unsigned b = (u & 0x80000000u) ? (u & 0x7FFFFFFFu) : ~u;
    return __uint_as_float(b);
}

static __device__ __forceinline__ void gload_lds16(const f16_t* g, f16_t* l) {
    __builtin_amdgcn_global_load_lds((const __attribute__((address_space(1))) unsigned*)g,
                                     (__attribute__((address_space(3))) unsigned*)l,
                                     16, 0, 0);
}

// ---------------- kernel 0: tri-unpack LUT + init per-row min ----------------
__global__ void k_lut(unsigned short* __restrict__ lut, unsigned* __restrict__ mind) {
    int k = blockIdx.x * 256 + threadIdx.x;
    if (k < KTOT) {
        int d = 0, e = 0;
        if (k < KQ) unpack_tri(k, d, e);
        lut[k] = (unsigned short)(d | (e << 8));
    }
    if (k < NPIX) mind[k] = 0xFFFFFFFFu;
}

// ---------------- kernel 1: projection f[n,d] = feat[:,n] . w[d,:] + b[d] ----------------
__global__ void k_proj(const float* __restrict__ feat, const float* __restrict__ w,
                       const float* __restrict__ b, float* __restrict__ f) {
    int gid = blockIdx.x * 256 + threadIdx.x;   // 409600 = 4096*100
    int n = gid & 4095;
    int d = gid >> 12;
    float acc = b[d];
    const float* wd = w + d * CIN;
    #pragma unroll 4
    for (int c = 0; c < CIN; ++c) acc += feat[c * 4096 + n] * wd[c];
    f[n * DP + d] = acc;
}

// ---------------- kernel 2: build A, register-image tiles ----------------
__global__ __launch_bounds__(256) void k_buildA(const float* __restrict__ f, const unsigned short* __restrict__ lut,
                                                f16_t* __restrict__ A) {
    __shared__ float fr[DP];
    int n = blockIdx.x;
    int t = threadIdx.x;
    if (t < DP) fr[t] = f[n * DP + t];
    __syncthreads();
    int r = n & 127;
    f16_t* tileBase = A + (size_t)(n >> 7) * KSTEPS * 8192;
    for (int g = t; g < KTOT / 8; g += 256) {
        int k0 = g * 8;
        u16x8 lu = *(const u16x8*)&lut[k0];
        f16x8 v;
        #pragma unroll
        for (int j = 0; j < 8; ++j) {
            int k = k0 + j;
            float x;
            if (k < KQ) {
                int d = lu[j] & 255, e = lu[j] >> 8;
                x = fr[d] * fr[e];
            } else if (k < KLIN) {
                x = fr[k - KQ];
            } else {
                x = 0.0f;
            }
            v[j] = (f16_t)x;
        }
        int kt = k0 >> 6, kin = k0 & 63;
        *(f16x8*)&tileBase[kt * 8192 + tile_idx(r, kin)] = v;
    }
}

// ---------------- kernel 3: build B, register-image tiles + const[l] ----------------
__global__ __launch_bounds__(256) void k_buildB(const float* __restrict__ icov, const float* __restrict__ mean,
                                                const unsigned short* __restrict__ lut,
                                                f16_t* __restrict__ Bm, float* __restrict__ constl) {
    __shared__ float ic[DP * 101];   // stride 101: conflict-free column reads
    __shared__ float ml[DP];
    __shared__ float wv[DP];
    __shared__ float part[DP];
    int l = blockIdx.x;
    int t = threadIdx.x;
    const float4* src4 = (const float4*)(icov + (size_t)l * DP * DP);
    for (int i4 = t; i4 < DP * DP / 4; i4 += 256) {
        float4 v = src4[i4];
        int flat = i4 * 4;
        int row = flat / 100;
        int col = flat - row * 100;   // 100 % 4 == 0: never crosses a row
        float* dst = &ic[row * 101 + col];
        dst[0] = v.x; dst[1] = v.y; dst[2] = v.z; dst[3] = v.w;
    }
    if (t < DP) ml[t] = mean[t * LNUM + l];
    __syncthreads();
    if (t < DP) {
        float icm = 0.f, ictm = 0.f;
        for (int e = 0; e < DP; ++e) {
            icm  += ic[t * 101 + e] * ml[e];
            ictm += ic[e * 101 + t] * ml[e];
        }
        wv[t]   = icm + ictm;        // (S m)_t  with S = IC + IC^T
        part[t] = ml[t] * icm;       // for m^T IC m
    }
    __syncthreads();
    if (t == 0) {
        float c = 0.f;
        for (int d = 0; d < DP; ++d) c += part[d];
        constl[l] = c;               // m^T IC m
    }
    int r = l & 127;
    f16_t* tileBase = Bm + (size_t)(l >> 7) * KSTEPS * 8192;
    for (int g = t; g < KTOT / 8; g += 256) {
        int k0 = g * 8;
        u16x8 lu = *(const u16x8*)&lut[k0];
        f16x8 v;
        #pragma unroll
        for (int j = 0; j < 8; ++j) {
            int k = k0 + j;
            float x;
            if (k < KQ) {
                int d = lu[j] & 255, e = lu[j] >> 8;
                float s = ic[d * 101 + e] + ic[e * 101 + d];
                x = (d == e) ? 0.5f * s : s;
            } else if (k < KLIN) {
                x = -wv[k - KQ];
            } else {
                x = 0.0f;
            }
            v[j] = (f16_t)x;
        }
        int kt = k0 >> 6, kin = k0 & 63;
        *(f16x8*)&tileBase[kt * 8192 + tile_idx(r, kin)] = v;
    }
}

// ---------------- kernel 4: 128^2 MFMA GEMM, 32x32x16 shape, register-image LDS ----------------
// r9 shell (proven 162us, occ 35%, 0 conflicts) with the MFMA shape swapped:
// 16 ds_read_b128 (all base+lane*16, compile-time block offsets) + 16 mfma_32x32x16
// per wave-K-step. acc = 2x2 f32x16 = 64 f32/lane (same budget as before).
__global__ __launch_bounds__(256, 2) void k_gemm(const f16_t* __restrict__ A, const f16_t* __restrict__ Bm,
                                                 const float* __restrict__ constl, unsigned* __restrict__ mind) {
    __shared__ __align__(16) f16_t sA[8192];
    __shared__ __align__(16) f16_t sB[8192];

    int bid = blockIdx.x;
    int pid = ((bid & 7) << 7) | (bid >> 3);       // XCD swizzle (1024 % 8 == 0, bijective)
    int group = pid >> 8;
    int pin = pid & 255;
    int bm = group * 8 + (pin & 7);
    int bn = pin >> 3;

    int t = threadIdx.x;
    int lane = t & 63;
    int w = t >> 6;
    int wr = w >> 1, wc = w & 1;

    f32x16 acc[2][2];
    #pragma unroll
    for (int i = 0; i < 2; ++i)
        #pragma unroll
        for (int j = 0; j < 2; ++j) acc[i][j] = (f32x16){0.f};

    const f16_t* Atile = A + (size_t)bm * KSTEPS * 8192;
    const f16_t* Btile = Bm + (size_t)bn * KSTEPS * 8192;

    int chunk0 = w * 2048;           // f16 offset of this wave's 4KB region
    int lofs = lane * 8;             // f16 offset of this lane's 16B within a 1KB chunk
    int fbase = lane * 8;            // fragment read base (register-image layout)

    for (int kt = 0; kt < KSTEPS; ++kt) {
        const f16_t* As = Atile + kt * 8192;
        const f16_t* Bs = Btile + kt * 8192;
        #pragma unroll
        for (int c = 0; c < 4; ++c) {
            gload_lds16(As + chunk0 + c * 512 + lofs, &sA[chunk0 + c * 512]);
            gload_lds16(Bs + chunk0 + c * 512 + lofs, &sB[chunk0 + c * 512]);
        }
        __syncthreads();   // vmcnt drain + barrier: tile ready
        #pragma unroll
        for (int ks = 0; ks < 4; ++ks) {
            f16x8 a0 = *(const f16x8*)&sA[((wr * 2 + 0) * 4 + ks) * 512 + fbase];
            f16x8 a1 = *(const f16x8*)&sA[((wr * 2 + 1) * 4 + ks) * 512 + fbase];
            f16x8 b0 = *(const f16x8*)&sB[((wc * 2 + 0) * 4 + ks) * 512 + fbase];
            f16x8 b1 = *(const f16x8*)&sB[((wc * 2 + 1) * 4 + ks) * 512 + fbase];
            acc[0][0] = __builtin_amdgcn_mfma_f32_32x32x16_f16(a0, b0, acc[0][0], 0, 0, 0);
            acc[0][1] = __builtin_amdgcn_mfma_f32_32x32x16_f16(a0, b1, acc[0][1], 0, 0, 0);
            acc[1][0] = __builtin_amdgcn_mfma_f32_32x32x16_f16(a1, b0, acc[1][0], 0, 0, 0);
            acc[1][1] = __builtin_amdgcn_mfma_f32_32x32x16_f16(a1, b1, acc[1][1], 0, 0, 0);
        }
        __syncthreads();   // all fragment reads done before next stage overwrites
    }

    // epilogue: dist = acc + const[col]; row-min over block cols; atomicMin
    // C/D 32x32 layout: col = lane&31, row = (reg&3) + 8*(reg>>2) + 4*(lane>>5)
    int l31 = lane & 31;
    int hi = lane >> 5;
    float cl[2];
    #pragma unroll
    for (int ct = 0; ct < 2; ++ct) cl[ct] = constl[bn * 128 + wc * 64 + ct * 32 + l31];
    #pragma unroll
    for (int rt = 0; rt < 2; ++rt) {
        #pragma unroll
        for (int j = 0; j < 16; ++j) {
            float v = fminf(acc[rt][0][j] + cl[0], acc[rt][1][j] + cl[1]);
            #pragma unroll
            for (int s = 1; s < 32; s <<= 1) v = fminf(v, __shfl_xor(v, s, 64));
            if (l31 == 0) {
                int row = bm * 128 + wr * 64 + rt * 32 + (j & 3) + 8 * (j >> 2) + 4 * hi;
                atomicMin(&mind[row], f2u(v));
            }
        }
    }
}

// ---------------- kernel 5: normalize + bilinear upsample (min/max fused per block) ----------------
__global__ __launch_bounds__(256) void k_upsample(const unsigned* __restrict__ mind, float* __restrict__ out) {
    __shared__ float smin[256], smax[256];
    int t = threadIdx.x;
    float vmin = 1e30f, vmax = -1e30f;
    for (int i = t; i < NPIX; i += 256) {
        float v = u2f(mind[i]);
        vmin = fminf(vmin, v);
        vmax = fmaxf(vmax, v);
    }
    smin[t] = vmin; smax[t] = vmax;
    __syncthreads();
    for (int s = 128; s > 0; s >>= 1) {
        if (t < s) {
            smin[t] = fminf(smin[t], smin[t + s]);
            smax[t] = fmaxf(smax[t], smax[t + s]);
        }
        __syncthreads();
    }
    float gmin = smin[0];
    float scale = 1.0f / (smax[0] - smin[0] + 1e-8f);

    int gid = blockIdx.x * 256 + t;             // 65536
    int i = gid >> 8, j = gid & 255;
    float x = fminf(fmaxf(j * 0.25f - 0.375f, 0.0f), 63.0f);
    float y = fminf(fmaxf(i * 0.25f - 0.375f, 0.0f), 63.0f);
    int x0 = (int)x, y0 = (int)y;
    int x1 = min(x0 + 1, 63), y1 = min(y0 + 1, 63);
    float fx = x - x0, fy = y - y0;
    float v00 = u2f(mind[y0 * 64 + x0]), v01 = u2f(mind[y0 * 64 + x1]);
    float v10 = u2f(mind[y1 * 64 + x0]), v11 = u2f(mind[y1 * 64 + x1]);
    float v = v00 * (1.f - fy) * (1.f - fx) + v01 * (1.f - fy) * fx
            + v10 * fy * (1.f - fx) + v11 * fy * fx;
    out[gid] = (v - gmin) * scale;
}

// ---------------- diagnostic: ws too small -> uniform 0.25 output (absmax ~0.70) ----------------
__global__ void k_diag(float* __restrict__ out) {
    int gid = blockIdx.x * 256 + threadIdx.x;
    out[gid] = 0.25f;
}

extern "C" void kernel_launch(void* const* d_in, const int* in_sizes, int n_in,
                              void* d_out, int out_size, void* d_ws, size_t ws_size,
                              hipStream_t stream) {
    const float* feat = (const float*)d_in[0];
    const float* pw   = (const float*)d_in[1];
    const float* pb   = (const float*)d_in[2];
    const float* mean = (const float*)d_in[3];
    const float* icov = (const float*)d_in[4];

    size_t need = 0;
    auto count = [&need](size_t bytes) { need = ((need + 255) & ~(size_t)255) + bytes; };
    count((size_t)NPIX * DP * 4);
    count((size_t)NPIX * KTOT * 2);
    count((size_t)LNUM * KTOT * 2);
    count((size_t)LNUM * 4);
    count((size_t)NPIX * 4);
    count((size_t)KTOT * 2);
    if (ws_size < need) {
        k_diag<<<256, 256, 0, stream>>>((float*)d_out);
        return;
    }

    char* ws = (char*)d_ws;
    size_t off = 0;
    auto alloc = [&](size_t bytes) -> void* {
        off = (off + 255) & ~(size_t)255;
        void* p = ws + off;
        off += bytes;
        return p;
    };
    float*          f      = (float*)alloc((size_t)NPIX * DP * 4);
    f16_t*          Amat   = (f16_t*)alloc((size_t)NPIX * KTOT * 2);
    f16_t*          Bmat   = (f16_t*)alloc((size_t)LNUM * KTOT * 2);
    float*          constl = (float*)alloc((size_t)LNUM * 4);
    unsigned*       mind   = (unsigned*)alloc((size_t)NPIX * 4);
    unsigned short* lut    = (unsigned short*)alloc((size_t)KTOT * 2);

    k_lut     <<<(KTOT + 255) / 256, 256, 0, stream>>>(lut, mind);
    k_proj    <<<1600, 256, 0, stream>>>(feat, pw, pb, f);
    k_buildA  <<<NPIX, 256, 0, stream>>>(f, lut, Amat);
    k_buildB  <<<LNUM, 256, 0, stream>>>(icov, mean, lut, Bmat, constl);
    k_gemm    <<<1024, 256, 0, stream>>>(Amat, Bmat, constl, mind);
    k_upsample<<<256, 256, 0, stream>>>(mind, (float*)d_out);
}

// Round 12
// 303.573 us; speedup vs baseline: 5.2606x; 1.1902x over previous
//
#include <hip/hip_runtime.h>
#include <hip/hip_bf16.h>
#include <stdint.h>

#define CIN   448
#define DP    100
#define NPIX  4096
#define LNUM  4096
#define KQ    5050      // packed upper-triangle columns
#define KLIN  5150      // + 100 linear columns
#define KTOT  5184      // padded to 81*64
#define KSTEPS (KTOT / 64)
#define OUTHW 256
#define ICS   104       // padded LDS stride for buildB (float4-aligned, odd/4 banks)

typedef _Float16 f16_t;
typedef _Float16 f16x8 __attribute__((ext_vector_type(8)));
typedef float    f32x4 __attribute__((ext_vector_type(4)));
typedef unsigned short u16x8 __attribute__((ext_vector_type(8)));

static __device__ __forceinline__ int tri_off(int d) { return (d * (201 - d)) >> 1; }

static __device__ __forceinline__ void unpack_tri(int k, int& d, int& e) {
    int dd = (int)((201.0f - sqrtf(40401.0f - 8.0f * (float)k)) * 0.5f);
    if (dd < 0) dd = 0;
    if (dd > 99) dd = 99;
    while (tri_off(dd + 1) <= k) ++dd;
    while (tri_off(dd) > k) --dd;
    d = dd;
    e = dd + (k - tri_off(dd));
}

static __device__ __forceinline__ unsigned f2u(float x) {
    unsigned b = __float_as_uint(x);
    return (b & 0x80000000u) ? ~b : (b | 0x80000000u);
}
static __device__ __forceinline__ float u2f(unsigned u) {
    unsigned b = (u & 0x80000000u) ? (u & 0x7FFFFFFFu) : ~u;
    return __uint_as_float(b);
}

static __device__ __forceinline__ void gload_lds16(const f16_t* g, f16_t* l) {
    __builtin_amdgcn_global_load_lds((const __attribute__((address_space(1))) unsigned*)g,
                                     (__attribute__((address_space(3))) unsigned*)l,
                                     16, 0, 0);
}

// ---------------- kernel 0: tri-unpack LUT + init per-row min ----------------
__global__ void k_lut(unsigned short* __restrict__ lut, unsigned* __restrict__ mind) {
    int k = blockIdx.x * 256 + threadIdx.x;
    if (k < KTOT) {
        int d = 0, e = 0;
        if (k < KQ) unpack_tri(k, d, e);
        lut[k] = (unsigned short)(d | (e << 8));
    }
    if (k < NPIX) mind[k] = 0xFFFFFFFFu;
}

// ---------------- kernel 1: projection f[n,d] = feat[:,n] . w[d,:] + b[d] ----------------
__global__ void k_proj(const float* __restrict__ feat, const float* __restrict__ w,
                       const float* __restrict__ b, float* __restrict__ f) {
    int gid = blockIdx.x * 256 + threadIdx.x;   // 409600 = 4096*100
    int n = gid & 4095;
    int d = gid >> 12;
    float acc = b[d];
    const float* wd = w + d * CIN;
    #pragma unroll 4
    for (int c = 0; c < CIN; ++c) acc += feat[c * 4096 + n] * wd[c];
    f[n * DP + d] = acc;
}

// ---------------- kernel 2: build A, tiled+swizzled (r9 verbatim) ----------------
__global__ __launch_bounds__(256) void k_buildA(const float* __restrict__ f, const unsigned short* __restrict__ lut,
                                                f16_t* __restrict__ A) {
    __shared__ float fr[DP];
    int n = blockIdx.x;
    int t = threadIdx.x;
    if (t < DP) fr[t] = f[n * DP + t];
    __syncthreads();
    int r  = n & 127;
    int rsw = (r & 7) << 3;
    f16_t* tileBase = A + (size_t)(n >> 7) * KSTEPS * 8192;
    for (int g = t; g < KTOT / 8; g += 256) {
        int k0 = g * 8;
        u16x8 lu = *(const u16x8*)&lut[k0];
        f16x8 v;
        #pragma unroll
        for (int j = 0; j < 8; ++j) {
            int k = k0 + j;
            float x;
            if (k < KQ) {
                int d = lu[j] & 255, e = lu[j] >> 8;
                x = fr[d] * fr[e];
            } else if (k < KLIN) {
                x = fr[k - KQ];
            } else {
                x = 0.0f;
            }
            v[j] = (f16_t)x;
        }
        int kt = k0 >> 6, kin = k0 & 63;
        *(f16x8*)&tileBase[kt * 8192 + r * 64 + ((kin & 56) ^ rsw)] = v;
    }
}

// ---------------- kernel 3: build B (ic stride 104, float4 icm) + const[l] ----------------
__global__ __launch_bounds__(256) void k_buildB(const float* __restrict__ icov, const float* __restrict__ mean,
                                                const unsigned short* __restrict__ lut,
                                                f16_t* __restrict__ Bm, float* __restrict__ constl) {
    __shared__ float ic[DP * ICS];
    __shared__ float ml[ICS];
    __shared__ float wv[DP];
    __shared__ float part[DP];
    int l = blockIdx.x;
    int t = threadIdx.x;
    const float4* src4 = (const float4*)(icov + (size_t)l * DP * DP);
    for (int i4 = t; i4 < DP * DP / 4; i4 += 256) {
        float4 v = src4[i4];
        int flat = i4 * 4;
        int row = flat / 100;
        int col = flat - row * 100;   // 100 % 4 == 0: never crosses a row
        float* dst = &ic[row * ICS + col];
        dst[0] = v.x; dst[1] = v.y; dst[2] = v.z; dst[3] = v.w;
    }
    // zero pads so float4 icm over e=0..103 is safe (NaN-free)
    if (t < DP) {
        ic[t * ICS + 100] = 0.f; ic[t * ICS + 101] = 0.f;
        ic[t * ICS + 102] = 0.f; ic[t * ICS + 103] = 0.f;
        ml[t] = mean[t * LNUM + l];
    }
    if (t >= DP && t < ICS) ml[t] = 0.f;
    __syncthreads();
    if (t < DP) {
        float icm = 0.f;
        const f32x4* icr = (const f32x4*)&ic[t * ICS];
        const f32x4* mlr = (const f32x4*)&ml[0];
        #pragma unroll
        for (int e4 = 0; e4 < ICS / 4; ++e4) {
            f32x4 a = icr[e4], m = mlr[e4];
            icm += a.x * m.x + a.y * m.y + a.z * m.z + a.w * m.w;
        }
        float ictm = 0.f;
        for (int e = 0; e < DP; ++e) ictm += ic[e * ICS + t] * ml[e];
        wv[t]   = icm + ictm;        // (S m)_t  with S = IC + IC^T
        part[t] = ml[t] * icm;       // for m^T IC m
    }
    __syncthreads();
    if (t == 0) {
        float c = 0.f;
        for (int d = 0; d < DP; ++d) c += part[d];
        constl[l] = c;               // m^T IC m
    }
    int r  = l & 127;
    int rsw = (r & 7) << 3;
    f16_t* tileBase = Bm + (size_t)(l >> 7) * KSTEPS * 8192;
    for (int g = t; g < KTOT / 8; g += 256) {
        int k0 = g * 8;
        u16x8 lu = *(const u16x8*)&lut[k0];
        f16x8 v;
        #pragma unroll
        for (int j = 0; j < 8; ++j) {
            int k = k0 + j;
            float x;
            if (k < KQ) {
                int d = lu[j] & 255, e = lu[j] >> 8;
                float s = ic[d * ICS + e] + ic[e * ICS + d];
                x = (d == e) ? 0.5f * s : s;
            } else if (k < KLIN) {
                x = -wv[k - KQ];
            } else {
                x = 0.0f;
            }
            v[j] = (f16_t)x;
        }
        int kt = k0 >> 6, kin = k0 & 63;
        *(f16x8*)&tileBase[kt * 8192 + r * 64 + ((kin & 56) ^ rsw)] = v;
    }
}

// ---------------- kernel 4: MFMA GEMM — r9 verbatim (162us, MfmaUtil 54.7%, 0 conflicts) ----------------
__global__ __launch_bounds__(256, 2) void k_gemm(const f16_t* __restrict__ A, const f16_t* __restrict__ Bm,
                                                 const float* __restrict__ constl, unsigned* __restrict__ mind) {
    __shared__ __align__(16) f16_t sA[8192];
    __shared__ __align__(16) f16_t sB[8192];

    int bid = blockIdx.x;
    int pid = ((bid & 7) << 7) | (bid >> 3);       // XCD swizzle (1024 % 8 == 0, bijective)
    int group = pid >> 8;
    int pin = pid & 255;
    int bm = group * 8 + (pin & 7);
    int bn = pin >> 3;

    int t = threadIdx.x;
    int lane = t & 63;
    int w = t >> 6;
    int wr = w >> 1, wc = w & 1;

    f32x4 acc[4][4];
    #pragma unroll
    for (int i = 0; i < 4; ++i)
        #pragma unroll
        for (int j = 0; j < 4; ++j) acc[i][j] = (f32x4){0.f, 0.f, 0.f, 0.f};

    const f16_t* Atile = A + (size_t)bm * KSTEPS * 8192;
    const f16_t* Btile = Bm + (size_t)bn * KSTEPS * 8192;

    int chunk0 = w * 2048;           // f16 offset of this wave's 4KB region
    int lofs = lane * 8;             // f16 offset of this lane's 16B within a 1KB chunk

    int arow[4], brow[4];
    #pragma unroll
    for (int i = 0; i < 4; ++i) {
        arow[i] = wr * 64 + i * 16 + (lane & 15);
        brow[i] = wc * 64 + i * 16 + (lane & 15);
    }

    for (int kt = 0; kt < KSTEPS; ++kt) {
        const f16_t* As = Atile + kt * 8192;
        const f16_t* Bs = Btile + kt * 8192;
        #pragma unroll
        for (int c = 0; c < 4; ++c) {
            gload_lds16(As + chunk0 + c * 512 + lofs, &sA[chunk0 + c * 512]);
            gload_lds16(Bs + chunk0 + c * 512 + lofs, &sB[chunk0 + c * 512]);
        }
        __syncthreads();   // vmcnt drain + barrier: tile ready
        #pragma unroll
        for (int kk = 0; kk < 2; ++kk) {
            f16x8 afr[4], bfr[4];
            int klo = kk * 32 + (lane >> 4) * 8;   // multiple of 8, 0..56
            #pragma unroll
            for (int mi = 0; mi < 4; ++mi)
                afr[mi] = *(const f16x8*)&sA[arow[mi] * 64 + (klo ^ ((arow[mi] & 7) << 3))];
            #pragma unroll
            for (int ni = 0; ni < 4; ++ni)
                bfr[ni] = *(const f16x8*)&sB[brow[ni] * 64 + (klo ^ ((brow[ni] & 7) << 3))];
            #pragma unroll
            for (int mi = 0; mi < 4; ++mi)
                #pragma unroll
                for (int ni = 0; ni < 4; ++ni)
                    acc[mi][ni] = __builtin_amdgcn_mfma_f32_16x16x32_f16(afr[mi], bfr[ni], acc[mi][ni], 0, 0, 0);
        }
        __syncthreads();   // all MFMA fragment reads done before next stage overwrites
    }

    // epilogue: dist = acc + const[col]; min over this block's cols per row; atomicMin
    int colbase = bn * 128 + wc * 64 + (lane & 15);
    float cl[4];
    #pragma unroll
    for (int ni = 0; ni < 4; ++ni) cl[ni] = constl[colbase + ni * 16];
    #pragma unroll
    for (int mi = 0; mi < 4; ++mi) {
        #pragma unroll
        for (int j = 0; j < 4; ++j) {
            float v = 1e30f;
            #pragma unroll
            for (int ni = 0; ni < 4; ++ni) v = fminf(v, acc[mi][ni][j] + cl[ni]);
            #pragma unroll
            for (int s = 1; s < 16; s <<= 1) v = fminf(v, __shfl_xor(v, s, 64));
            if ((lane & 15) == 0) {
                int row = bm * 128 + wr * 64 + mi * 16 + (lane >> 4) * 4 + j;
                atomicMin(&mind[row], f2u(v));
            }
        }
    }
}

// ---------------- kernel 5: normalize + bilinear upsample (min/max fused per block) ----------------
__global__ __launch_bounds__(256) void k_upsample(const unsigned* __restrict__ mind, float* __restrict__ out) {
    __shared__ float smin[256], smax[256];
    int t = threadIdx.x;
    float vmin = 1e30f, vmax = -1e30f;
    for (int i = t; i < NPIX; i += 256) {
        float v = u2f(mind[i]);
        vmin = fminf(vmin, v);
        vmax = fmaxf(vmax, v);
    }
    smin[t] = vmin; smax[t] = vmax;
    __syncthreads();
    for (int s = 128; s > 0; s >>= 1) {
        if (t < s) {
            smin[t] = fminf(smin[t], smin[t + s]);
            smax[t] = fmaxf(smax[t], smax[t + s]);
        }
        __syncthreads();
    }
    float gmin = smin[0];
    float scale = 1.0f / (smax[0] - smin[0] + 1e-8f);

    int gid = blockIdx.x * 256 + t;             // 65536
    int i = gid >> 8, j = gid & 255;
    float x = fminf(fmaxf(j * 0.25f - 0.375f, 0.0f), 63.0f);
    float y = fminf(fmaxf(i * 0.25f - 0.375f, 0.0f), 63.0f);
    int x0 = (int)x, y0 = (int)y;
    int x1 = min(x0 + 1, 63), y1 = min(y0 + 1, 63);
    float fx = x - x0, fy = y - y0;
    float v00 = u2f(mind[y0 * 64 + x0]), v01 = u2f(mind[y0 * 64 + x1]);
    float v10 = u2f(mind[y1 * 64 + x0]), v11 = u2f(mind[y1 * 64 + x1]);
    float v = v00 * (1.f - fy) * (1.f - fx) + v01 * (1.f - fy) * fx
            + v10 * fy * (1.f - fx) + v11 * fy * fx;
    out[gid] = (v - gmin) * scale;
}

// ---------------- diagnostic: ws too small -> uniform 0.25 output (absmax ~0.70) ----------------
__global__ void k_diag(float* __restrict__ out) {
    int gid = blockIdx.x * 256 + threadIdx.x;
    out[gid] = 0.25f;
}

extern "C" void kernel_launch(void* const* d_in, const int* in_sizes, int n_in,
                              void* d_out, int out_size, void* d_ws, size_t ws_size,
                              hipStream_t stream) {
    const float* feat = (const float*)d_in[0];
    const float* pw   = (const float*)d_in[1];
    const float* pb   = (const float*)d_in[2];
    const float* mean = (const float*)d_in[3];
    const float* icov = (const float*)d_in[4];

    size_t need = 0;
    auto count = [&need](size_t bytes) { need = ((need + 255) & ~(size_t)255) + bytes; };
    count((size_t)NPIX * DP * 4);
    count((size_t)NPIX * KTOT * 2);
    count((size_t)LNUM * KTOT * 2);
    count((size_t)LNUM * 4);
    count((size_t)NPIX * 4);
    count((size_t)KTOT * 2);
    if (ws_size < need) {
        k_diag<<<256, 256, 0, stream>>>((float*)d_out);
        return;
    }

    char* ws = (char*)d_ws;
    size_t off = 0;
    auto alloc = [&](size_t bytes) -> void* {
        off = (off + 255) & ~(size_t)255;
        void* p = ws + off;
        off += bytes;
        return p;
    };
    float*          f      = (float*)alloc((size_t)NPIX * DP * 4);
    f16_t*          Amat   = (f16_t*)alloc((size_t)NPIX * KTOT * 2);
    f16_t*          Bmat   = (f16_t*)alloc((size_t)LNUM * KTOT * 2);
    float*          constl = (float*)alloc((size_t)LNUM * 4);
    unsigned*       mind   = (unsigned*)alloc((size_t)NPIX * 4);
    unsigned short* lut    = (unsigned short*)alloc((size_t)KTOT * 2);

    k_lut     <<<(KTOT + 255) / 256, 256, 0, stream>>>(lut, mind);
    k_proj    <<<1600, 256, 0, stream>>>(feat, pw, pb, f);
    k_buildA  <<<NPIX, 256, 0, stream>>>(f, lut, Amat);
    k_buildB  <<<LNUM, 256, 0, stream>>>(icov, mean, lut, Bmat, constl);
    k_gemm    <<<1024, 256, 0, stream>>>(Amat, Bmat, constl, mind);
    k_upsample<<<256, 256, 0, stream>>>(mind, (float*)d_out);
}